// Round 3
// baseline (134.476 us; speedup 1.0000x reference)
//
#include <hip/hip_runtime.h>
#include <hip/hip_cooperative_groups.h>

namespace cg = cooperative_groups;

// Problem constants (from reference): B=128, T=32, D=512, R=256, R2=128.
// Analytical collapse: r_new = zeros every scan step and r2 stays zeros, so
// r_p = 0 -> r_bar = 0 -> temp_loss = 0, x_hat = x_bar = b_sd. Remaining work:
//   sl_rhat = sum_t mean_b sum_d (b_sd[d] - X[b,t,d])^2
//   sl_rbar = sl_rhat - (t==0 term)
// Outputs (flat, 49156 f32): [sl_rhat, sl_rbar, 0, 0, r0=zeros(32768), r2=zeros(16384)]
//
// R3: single cooperative kernel (grid sync replaces the second launch).
// 256 blocks x 256 threads = 1 block/CU -> trivially co-resident.

#define BB 128
#define TT 32
#define DD 512
#define NBLK 256

__global__ void __launch_bounds__(256) k_all(const float* __restrict__ X,
                                             const float* __restrict__ b_sd,
                                             float* __restrict__ out,
                                             float* __restrict__ ws) {
    const int tid  = blockIdx.x * blockDim.x + threadIdx.x;
    const int lane = threadIdx.x & 63, wid = threadIdx.x >> 6;

    // --- zero out[4 .. 49155] (12288 float4s; 65536 threads -> first 12288) ---
    {
        float4* __restrict__ o4 = (float4*)(out + 4);
        const int nz4 = (BB * 256 + BB * 128) / 4;  // 12288
        if (tid < nz4) o4[tid] = make_float4(0.f, 0.f, 0.f, 0.f);
    }

    // --- reduce sum of (X - b_sd)^2, all-t and t==0 slice ---
    const int n4  = BB * TT * DD / 4;      // 524288 float4s
    const int d4n = DD / 4;                // 128 float4s per (b,t) row
    const float4* __restrict__ X4 = (const float4*)X;
    const float4* __restrict__ B4 = (const float4*)b_sd;

    float acc_all = 0.0f, acc_t0 = 0.0f;
    for (int i = tid; i < n4; i += NBLK * 256) {   // 8 float4 per thread
        int row = i / d4n;                 // = b*T + t
        int t   = row & (TT - 1);          // T = 32 (pow2)
        int d4  = i - row * d4n;
        float4 x = X4[i];
        float4 c = B4[d4];
        float ex = x.x - c.x, ey = x.y - c.y, ez = x.z - c.z, ew = x.w - c.w;
        float s = ex * ex + ey * ey + ez * ez + ew * ew;
        acc_all += s;
        if (t == 0) acc_t0 += s;
    }

    for (int off = 32; off > 0; off >>= 1) {
        acc_all += __shfl_down(acc_all, off, 64);
        acc_t0  += __shfl_down(acc_t0, off, 64);
    }
    __shared__ float s_all[4], s_t0[4];
    if (lane == 0) { s_all[wid] = acc_all; s_t0[wid] = acc_t0; }
    __syncthreads();
    if (threadIdx.x == 0) {
        ws[blockIdx.x]       = s_all[0] + s_all[1] + s_all[2] + s_all[3];
        ws[512 + blockIdx.x] = s_t0[0]  + s_t0[1]  + s_t0[2]  + s_t0[3];
    }

    cg::this_grid().sync();   // device-scope barrier; partials visible after

    // --- block 0: final reduce of 2x256 partials + scalar writes ---
    if (blockIdx.x == 0) {
        const int t = threadIdx.x;
        float a  = ws[t];
        float z  = ws[512 + t];
        for (int off = 32; off > 0; off >>= 1) {
            a += __shfl_down(a, off, 64);
            z += __shfl_down(z, off, 64);
        }
        __shared__ float f_a[4], f_t[4];
        if (lane == 0) { f_a[wid] = a; f_t[wid] = z; }
        __syncthreads();
        if (t == 0) {
            float all = f_a[0] + f_a[1] + f_a[2] + f_a[3];
            float z0  = f_t[0] + f_t[1] + f_t[2] + f_t[3];
            const float invB = 1.0f / (float)BB;
            out[0] = all * invB;          // sl_rhat
            out[1] = (all - z0) * invB;   // sl_rbar
            out[2] = 0.0f;                // TEMP_WEIGHT * temp_loss
            out[3] = 0.0f;                // r2_losses
        }
    }
}

extern "C" void kernel_launch(void* const* d_in, const int* in_sizes, int n_in,
                              void* d_out, int out_size, void* d_ws, size_t ws_size,
                              hipStream_t stream) {
    const float* X    = (const float*)d_in[0];   // (B,T,D)
    const float* b_sd = (const float*)d_in[3];   // (D,)
    float* out = (float*)d_out;                  // 49156 floats
    float* ws  = (float*)d_ws;

    dim3 grid(NBLK), block(256);
    void* args[] = {(void*)&X, (void*)&b_sd, (void*)&out, (void*)&ws};
    hipLaunchCooperativeKernel((void*)k_all, grid, block, args, 0, stream);
}

// Round 4
// 92.843 us; speedup vs baseline: 1.4484x; 1.4484x over previous
//
#include <hip/hip_runtime.h>

// Problem constants (from reference): B=128, T=32, D=512, R=256, R2=128.
// Analytical collapse: r_new = zeros every scan step and r2 stays zeros, so
// r_p = 0 -> r_bar = 0 -> temp_loss = 0, x_hat = x_bar = b_sd. Remaining work:
//   sl_rhat = sum_t mean_b sum_d (b_sd[d] - X[b,t,d])^2
//   sl_rbar = sl_rhat - (t==0 term)
// Outputs (flat, 49156 f32): [sl_rhat, sl_rbar, 0, 0, r0=zeros(32768), r2=zeros(16384)]
//
// R4: ONE regular kernel. Per-block partials go straight into out[0]/out[1]
// via atomicAdd (pre-scaled by 1/B). d_out poison base is 0xAAAAAAAA =
// -3.03e-13f -- negligible vs values ~1.6e4 and threshold 327.68; the
// correctness pass memsets out to 0 first anyway. No ws, no second launch,
// no coop launch (R3 showed coop dispatch costs ~+52us in graph replay).

#define BB 128
#define TT 32
#define DD 512
#define NBLK 512

__global__ void __launch_bounds__(256) k_all(const float* __restrict__ X,
                                             const float* __restrict__ b_sd,
                                             float* __restrict__ out) {
    const int tid  = blockIdx.x * blockDim.x + threadIdx.x;
    const int lane = threadIdx.x & 63, wid = threadIdx.x >> 6;

    // --- zero out[4 .. 49155] (12288 float4s starting at out+4, 16B-aligned) ---
    {
        float4* __restrict__ o4 = (float4*)(out + 4);
        const int nz4 = (BB * 256 + BB * 128) / 4;  // 12288
        if (tid < nz4) o4[tid] = make_float4(0.f, 0.f, 0.f, 0.f);
    }
    // --- scalars out[2], out[3] (distinct addresses from the atomics) ---
    if (tid == 0) { out[2] = 0.0f; out[3] = 0.0f; }

    // --- reduce sum of (X - b_sd)^2, all-t and t==0 slice ---
    const int n4  = BB * TT * DD / 4;      // 524288 float4s
    const int d4n = DD / 4;                // 128 float4s per (b,t) row
    const float4* __restrict__ X4 = (const float4*)X;
    const float4* __restrict__ B4 = (const float4*)b_sd;

    float acc_all = 0.0f, acc_t0 = 0.0f;
    for (int i = tid; i < n4; i += NBLK * 256) {   // 4 float4 per thread
        int row = i / d4n;                 // = b*T + t  (const divide -> shift)
        int t   = row & (TT - 1);          // T = 32 (pow2)
        int d4  = i - row * d4n;
        float4 x = X4[i];
        float4 c = B4[d4];
        float ex = x.x - c.x, ey = x.y - c.y, ez = x.z - c.z, ew = x.w - c.w;
        float s = ex * ex + ey * ey + ez * ez + ew * ew;
        acc_all += s;
        if (t == 0) acc_t0 += s;
    }

    // wave-64 reduce
    for (int off = 32; off > 0; off >>= 1) {
        acc_all += __shfl_down(acc_all, off, 64);
        acc_t0  += __shfl_down(acc_t0, off, 64);
    }
    __shared__ float s_all[4], s_t0[4];
    if (lane == 0) { s_all[wid] = acc_all; s_t0[wid] = acc_t0; }
    __syncthreads();
    if (threadIdx.x == 0) {
        const float invB = 1.0f / (float)BB;
        float a  = s_all[0] + s_all[1] + s_all[2] + s_all[3];
        float z0 = s_t0[0]  + s_t0[1]  + s_t0[2]  + s_t0[3];
        atomicAdd(&out[0], a * invB);          // sl_rhat partial
        atomicAdd(&out[1], (a - z0) * invB);   // sl_rbar partial
    }
}

extern "C" void kernel_launch(void* const* d_in, const int* in_sizes, int n_in,
                              void* d_out, int out_size, void* d_ws, size_t ws_size,
                              hipStream_t stream) {
    const float* X    = (const float*)d_in[0];   // (B,T,D)
    const float* b_sd = (const float*)d_in[3];   // (D,)
    float* out = (float*)d_out;                  // 49156 floats

    k_all<<<NBLK, 256, 0, stream>>>(X, b_sd, out);
}

// Round 6
// 85.694 us; speedup vs baseline: 1.5693x; 1.0834x over previous
//
#include <hip/hip_runtime.h>

// Problem constants (from reference): B=128, T=32, D=512, R=256, R2=128.
// Analytical collapse: r_new = zeros every scan step and r2 stays zeros, so
// r_p = 0 -> r_bar = 0 -> temp_loss = 0, x_hat = x_bar = b_sd. Remaining work:
//   sl_rhat = sum_t mean_b sum_d (b_sd[d] - X[b,t,d])^2
//   sl_rbar = sl_rhat - (t==0 term)
// Outputs (flat, 49156 f32): [sl_rhat, sl_rbar, 0, 0, r0=zeros(32768), r2=zeros(16384)]
//
// R6: ONE regular kernel; producer/consumer via a SEPARATE FLAG slot.
// R5 hung because 480/512 blocks have a legitimately-zero t0 partial (only
// blocks with 256b % 4096 == 0 touch t==0 rows) and the consumer spun on the
// data value. Now: producers relaxed-store data, release-store flag=1.0f;
// block 0 acquire-spins on flag > 0.5f (poison 0xAA... = -3e-13 and zeroed ws
// both spin until the real flag lands), then relaxed-loads data.
// ws layout: [0..511]=a partials, [512..1023]=t0 partials, [1024..1535]=flags.

#define BB 128
#define TT 32
#define DD 512
#define NBLK 512

__global__ void __launch_bounds__(256) k_all(const float* __restrict__ X,
                                             const float* __restrict__ b_sd,
                                             float* __restrict__ out,
                                             float* __restrict__ ws) {
    const int tid  = blockIdx.x * blockDim.x + threadIdx.x;
    const int lane = threadIdx.x & 63, wid = threadIdx.x >> 6;

    // --- zero out[4 .. 49155] (12288 float4s starting at out+4, 16B-aligned) ---
    {
        float4* __restrict__ o4 = (float4*)(out + 4);
        const int nz4 = (BB * 256 + BB * 128) / 4;  // 12288
        if (tid < nz4) o4[tid] = make_float4(0.f, 0.f, 0.f, 0.f);
    }

    // --- reduce sum of (X - b_sd)^2, all-t and t==0 slice ---
    const int n4  = BB * TT * DD / 4;      // 524288 float4s
    const int d4n = DD / 4;                // 128 float4s per (b,t) row
    const float4* __restrict__ X4 = (const float4*)X;
    const float4* __restrict__ B4 = (const float4*)b_sd;

    float acc_all = 0.0f, acc_t0 = 0.0f;
    for (int i = tid; i < n4; i += NBLK * 256) {   // 4 float4 per thread
        int row = i / d4n;                 // = b*T + t  (const divide -> shift)
        int t   = row & (TT - 1);          // T = 32 (pow2)
        int d4  = i - row * d4n;
        float4 x = X4[i];
        float4 c = B4[d4];
        float ex = x.x - c.x, ey = x.y - c.y, ez = x.z - c.z, ew = x.w - c.w;
        float s = ex * ex + ey * ey + ez * ez + ew * ew;
        acc_all += s;
        if (t == 0) acc_t0 += s;
    }

    // wave-64 reduce
    for (int off = 32; off > 0; off >>= 1) {
        acc_all += __shfl_down(acc_all, off, 64);
        acc_t0  += __shfl_down(acc_t0, off, 64);
    }
    __shared__ float s_all[4], s_t0[4];
    if (lane == 0) { s_all[wid] = acc_all; s_t0[wid] = acc_t0; }
    __syncthreads();
    if (threadIdx.x == 0) {
        float a  = s_all[0] + s_all[1] + s_all[2] + s_all[3];
        float z0 = s_t0[0]  + s_t0[1]  + s_t0[2]  + s_t0[3];
        __hip_atomic_store(&ws[blockIdx.x], a, __ATOMIC_RELAXED,
                           __HIP_MEMORY_SCOPE_AGENT);
        __hip_atomic_store(&ws[NBLK + blockIdx.x], z0, __ATOMIC_RELAXED,
                           __HIP_MEMORY_SCOPE_AGENT);
        // flag published AFTER data, release-ordered
        __hip_atomic_store(&ws[2 * NBLK + blockIdx.x], 1.0f, __ATOMIC_RELEASE,
                           __HIP_MEMORY_SCOPE_AGENT);
    }

    // --- block 0: consume the 2x512 partials once flags are up ---
    if (blockIdx.x == 0) {
        const int t = threadIdx.x;
        float f;
        do { f = __hip_atomic_load(&ws[2 * NBLK + t], __ATOMIC_ACQUIRE,
                                   __HIP_MEMORY_SCOPE_AGENT); } while (f < 0.5f);
        do { f = __hip_atomic_load(&ws[2 * NBLK + t + 256], __ATOMIC_ACQUIRE,
                                   __HIP_MEMORY_SCOPE_AGENT); } while (f < 0.5f);
        float a0 = __hip_atomic_load(&ws[t], __ATOMIC_RELAXED,
                                     __HIP_MEMORY_SCOPE_AGENT);
        float a1 = __hip_atomic_load(&ws[t + 256], __ATOMIC_RELAXED,
                                     __HIP_MEMORY_SCOPE_AGENT);
        float z0 = __hip_atomic_load(&ws[NBLK + t], __ATOMIC_RELAXED,
                                     __HIP_MEMORY_SCOPE_AGENT);
        float z1 = __hip_atomic_load(&ws[NBLK + t + 256], __ATOMIC_RELAXED,
                                     __HIP_MEMORY_SCOPE_AGENT);
        float a = a0 + a1;          // same pairwise order as R2's k_final
        float z = z0 + z1;
        for (int off = 32; off > 0; off >>= 1) {
            a += __shfl_down(a, off, 64);
            z += __shfl_down(z, off, 64);
        }
        __shared__ float f_a[4], f_t[4];
        if (lane == 0) { f_a[wid] = a; f_t[wid] = z; }
        __syncthreads();
        if (t == 0) {
            float all = f_a[0] + f_a[1] + f_a[2] + f_a[3];
            float zz  = f_t[0] + f_t[1] + f_t[2] + f_t[3];
            const float invB = 1.0f / (float)BB;
            out[0] = all * invB;          // sl_rhat
            out[1] = (all - zz) * invB;   // sl_rbar
            out[2] = 0.0f;                // TEMP_WEIGHT * temp_loss
            out[3] = 0.0f;                // r2_losses
        }
    }
}

extern "C" void kernel_launch(void* const* d_in, const int* in_sizes, int n_in,
                              void* d_out, int out_size, void* d_ws, size_t ws_size,
                              hipStream_t stream) {
    const float* X    = (const float*)d_in[0];   // (B,T,D)
    const float* b_sd = (const float*)d_in[3];   // (D,)
    float* out = (float*)d_out;                  // 49156 floats
    float* ws  = (float*)d_ws;

    k_all<<<NBLK, 256, 0, stream>>>(X, b_sd, out, ws);
}

// Round 7
// 82.381 us; speedup vs baseline: 1.6324x; 1.0402x over previous
//
#include <hip/hip_runtime.h>

// Problem constants (from reference): B=128, T=32, D=512, R=256, R2=128.
// Analytical collapse: r_new = zeros every scan step and r2 stays zeros, so
// r_p = 0 -> r_bar = 0 -> temp_loss = 0, x_hat = x_bar = b_sd. The only
// nontrivial compute is:
//   sl_rhat = sum_t mean_b sum_d (b_sd[d] - X[b,t,d])^2   (t = 0..T-1)
//   sl_rbar = sl_rhat - (t==0 term)
// Outputs (flat, 49156 f32): [sl_rhat, sl_rbar, 0, 0, r0=zeros(32768), r2=zeros(16384)]
//
// FINAL (= R2 structure, measured best of 5 structures):
//   R1 3-kernel + same-line atomics: 96.6us | R2 2-kernel ws-slots: 82.4us
//   R3 cooperative 1-kernel: 134.5us (coop dispatch ~+50us in graph replay)
//   R4 1-kernel + same-line atomics: 92.8us (1024 same-line fp32 atomics ~+10us)
//   R6 1-kernel + flag spin-wait: 85.7us (consumer camps a CU polling flags)
// Per-graph-node cost ~2us < any cross-block-sync overhead -> 2 kernels wins.
//  k_main  (512 blocks): zero out[4..], reduce partials, write per-block ws slots
//                        (unconditional writes -> poisoned ws needs no init).
//  k_final (1 block):    sum 2x512 partials, write out[0..3].

#define BB 128
#define TT 32
#define DD 512
#define NBLK 512

__global__ void __launch_bounds__(256) k_main(const float* __restrict__ X,
                                              const float* __restrict__ b_sd,
                                              float* __restrict__ out,
                                              float* __restrict__ ws) {
    const int tid = blockIdx.x * blockDim.x + threadIdx.x;

    // --- zero out[4 .. 49155] (12288 float4s starting at out+4, 16B-aligned) ---
    {
        float4* __restrict__ o4 = (float4*)(out + 4);
        const int nz4 = (BB * 256 + BB * 128) / 4;  // r0 + r2 = 49152 floats = 12288 f4
        if (tid < nz4) o4[tid] = make_float4(0.f, 0.f, 0.f, 0.f);
    }

    // --- reduce sum of (X - b_sd)^2, all-t and t==0 slice ---
    const int n4  = BB * TT * DD / 4;      // 524288 float4s
    const int d4n = DD / 4;                // 128 float4s per (b,t) row
    const float4* __restrict__ X4 = (const float4*)X;
    const float4* __restrict__ B4 = (const float4*)b_sd;

    float acc_all = 0.0f, acc_t0 = 0.0f;
    for (int i = tid; i < n4; i += NBLK * 256) {   // 4 float4 per thread
        int row = i / d4n;                 // = b*T + t
        int t   = row & (TT - 1);          // T = 32 (pow2)
        int d4  = i - row * d4n;
        float4 x = X4[i];
        float4 c = B4[d4];
        float ex = x.x - c.x, ey = x.y - c.y, ez = x.z - c.z, ew = x.w - c.w;
        float s = ex * ex + ey * ey + ez * ez + ew * ew;
        acc_all += s;
        if (t == 0) acc_t0 += s;
    }

    // wave-64 butterfly reduce
    for (int off = 32; off > 0; off >>= 1) {
        acc_all += __shfl_down(acc_all, off, 64);
        acc_t0  += __shfl_down(acc_t0, off, 64);
    }
    __shared__ float s_all[4], s_t0[4];
    const int lane = threadIdx.x & 63, wid = threadIdx.x >> 6;
    if (lane == 0) { s_all[wid] = acc_all; s_t0[wid] = acc_t0; }
    __syncthreads();
    if (threadIdx.x == 0) {
        // unconditional per-block slot writes: poisoned ws needs no init
        ws[blockIdx.x]        = s_all[0] + s_all[1] + s_all[2] + s_all[3];
        ws[1024 + blockIdx.x] = s_t0[0]  + s_t0[1]  + s_t0[2]  + s_t0[3];
    }
}

__global__ void __launch_bounds__(256) k_final(const float* __restrict__ ws,
                                               float* __restrict__ out) {
    const int t = threadIdx.x;
    float a  = ws[t]        + ws[t + 256];         // 512 partials, 2/thread
    float t0 = ws[1024 + t] + ws[1024 + t + 256];
    for (int off = 32; off > 0; off >>= 1) {
        a  += __shfl_down(a, off, 64);
        t0 += __shfl_down(t0, off, 64);
    }
    __shared__ float s_a[4], s_t[4];
    const int lane = t & 63, wid = t >> 6;
    if (lane == 0) { s_a[wid] = a; s_t[wid] = t0; }
    __syncthreads();
    if (t == 0) {
        float all = s_a[0] + s_a[1] + s_a[2] + s_a[3];
        float z0  = s_t[0] + s_t[1] + s_t[2] + s_t[3];
        const float invB = 1.0f / (float)BB;
        out[0] = all * invB;          // sl_rhat
        out[1] = (all - z0) * invB;   // sl_rbar
        out[2] = 0.0f;                // TEMP_WEIGHT * temp_loss
        out[3] = 0.0f;                // r2_losses
    }
}

extern "C" void kernel_launch(void* const* d_in, const int* in_sizes, int n_in,
                              void* d_out, int out_size, void* d_ws, size_t ws_size,
                              hipStream_t stream) {
    const float* X    = (const float*)d_in[0];   // (B,T,D)
    const float* b_sd = (const float*)d_in[3];   // (D,)
    float* out = (float*)d_out;                  // 49156 floats
    float* ws  = (float*)d_ws;

    k_main<<<NBLK, 256, 0, stream>>>(X, b_sd, out, ws);
    k_final<<<1, 256, 0, stream>>>(ws, out);
}